// Round 19
// baseline (1272.956 us; speedup 1.0000x reference)
//
#include <hip/hip_runtime.h>

typedef unsigned int u32;
typedef unsigned short u16;
typedef unsigned long long u64;
typedef short bf16x8 __attribute__((ext_vector_type(8)));
typedef float f32x4 __attribute__((ext_vector_type(4)));

#define S1 12544      // 112*112
#define NSTAT 200704  // 16*112*112
#define EPS 1e-5f
#define AP 264        // padded A-tile row length (fused path)

__device__ __forceinline__ u16 f2bf(float f) {
  union { float f; u32 u; } x; x.f = f;
  u32 r = x.u + 0x7fffu + ((x.u >> 16) & 1u);
  return (u16)(r >> 16);
}
__device__ __forceinline__ void bf2x2(u32 u, float& lo, float& hi) {
  union { u32 u; float f; } a, b;
  a.u = u << 16; b.u = u & 0xffff0000u;
  lo = a.f; hi = b.f;
}
__device__ __forceinline__ float sigm(float x) { return 1.f / (1.f + expf(-x)); }

// ---------------- conv1 (3->256, 3x3, stride2, pad1) + bn1 stats ----------------
#define CW 225
__global__ __launch_bounds__(256) void k_conv1(const float* __restrict__ img,
    const float* __restrict__ w, u16* __restrict__ out, float* __restrict__ stats) {
  int blk = blockIdx.x;
  int b = blk / 56, strip = blk - b * 56;
  int r0 = strip * 2;
  int c = threadIdx.x;
  __shared__ float simg[3 * 5 * CW];
  const float* ib = img + (size_t)b * 3 * 224 * 224;
  for (int i = c; i < 3 * 5 * CW; i += 256) {
    int ch = i / (5 * CW);
    int rem = i - ch * (5 * CW);
    int lr = rem / CW;
    int col = rem - lr * CW;
    int ih = 2 * r0 - 1 + lr;
    int iw = col - 1;
    float v = 0.f;
    if (ih >= 0 && ih < 224 && iw >= 0 && iw < 224) v = ib[((size_t)ch * 224 + ih) * 224 + iw];
    simg[i] = v;
  }
  float wr[27];
#pragma unroll
  for (int i = 0; i < 27; i++) wr[i] = w[c * 27 + i];
  __syncthreads();
  float s = 0.f, q = 0.f;
  for (int orow = 0; orow < 2; orow++) {
    int oh = r0 + orow;
    for (int ow = 0; ow < 112; ow++) {
      float acc = 0.f;
#pragma unroll
      for (int ch = 0; ch < 3; ch++)
#pragma unroll
        for (int dr = 0; dr < 3; dr++) {
          const float* rp = &simg[(ch * 5 + 2 * orow + dr) * CW + 2 * ow];
          acc = fmaf(wr[(ch * 3 + dr) * 3 + 0], rp[0], acc);
          acc = fmaf(wr[(ch * 3 + dr) * 3 + 1], rp[1], acc);
          acc = fmaf(wr[(ch * 3 + dr) * 3 + 2], rp[2], acc);
        }
      s += acc; q = fmaf(acc, acc, q);
      out[((size_t)(b * 112 + oh) * 112 + ow) * 256 + c] = f2bf(acc);
    }
  }
  atomicAdd(&stats[c], s);
  atomicAdd(&stats[256 + c], q);
}

// ---------------- bn finalize ----------------
__global__ void k_bnfin(const float* __restrict__ stats, const float* __restrict__ g,
                        const float* __restrict__ bb, float* __restrict__ par, int C, float invN) {
  int c = blockIdx.x * 256 + threadIdx.x;
  if (c < C) {
    float m = stats[c] * invN;
    float v = stats[C + c] * invN - m * m;
    float sc = g[c] * rsqrtf(v + EPS);
    par[c] = sc;
    par[C + c] = bb[c] - m * sc;
  }
}

// ---------------- fp32 -> bf16 x4 ----------------
__global__ void k_cvt4(const float* __restrict__ w, u16* __restrict__ o, int n4) {
  int i = blockIdx.x * 256 + threadIdx.x;
  if (i < n4) {
    float4 v = ((const float4*)w)[i];
    union { u16 h[4]; uint2 u; } pk;
    pk.h[0] = f2bf(v.x); pk.h[1] = f2bf(v.y); pk.h[2] = f2bf(v.z); pk.h[3] = f2bf(v.w);
    ((uint2*)o)[i] = pk.u;
  }
}

// ---- shared sliding-window dw macro (uses locals: ib, c4, sc, sh, act) ----
#define LD_COL(ohv, iwv, slot) do {                                          \
    int _oh = (ohv), _iw = (iwv);                                            \
  _Pragma("unroll")                                                          \
    for (int _dr = 0; _dr < 3; _dr++) {                                      \
      int _ih = _oh - 1 + _dr;                                               \
      float _x0 = 0.f, _x1 = 0.f, _x2 = 0.f, _x3 = 0.f;                      \
      if (_ih >= 0 && _ih < 112 && _iw >= 0 && _iw < 112) {                  \
        uint2 _v = *(const uint2*)(ib + ((size_t)(_ih * 112 + _iw)) * 256 + c4); \
        float _t0, _t1, _t2, _t3;                                            \
        bf2x2(_v.x, _t0, _t1); bf2x2(_v.y, _t2, _t3);                        \
        _x0 = fmaxf(fmaf(_t0, sc[0], sh[0]), 0.f);                           \
        _x1 = fmaxf(fmaf(_t1, sc[1], sh[1]), 0.f);                           \
        _x2 = fmaxf(fmaf(_t2, sc[2], sh[2]), 0.f);                           \
        _x3 = fmaxf(fmaf(_t3, sc[3], sh[3]), 0.f);                           \
      }                                                                      \
      act[_dr][slot][0] = _x0; act[_dr][slot][1] = _x1;                      \
      act[_dr][slot][2] = _x2; act[_dr][slot][3] = _x3;                      \
    }                                                                        \
  } while (0)

// ---------------- standalone dw kernel (big-ws path): conv1out -> dwout bf16 ----------------
__global__ __launch_bounds__(256) void k_dws(const u16* __restrict__ cin,
    const float* __restrict__ bn1p, const float* __restrict__ dww, u16* __restrict__ out) {
  int tid = threadIdx.x;
  int wave = tid >> 6, lane = tid & 63;
  int c4 = lane * 4;
  int m0 = blockIdx.x * 64;
  int bimg = blockIdx.x / 196;
  float sc[4], sh[4], w9[4][9];
#pragma unroll
  for (int cc = 0; cc < 4; cc++) {
    sc[cc] = bn1p[c4 + cc];
    sh[cc] = bn1p[256 + c4 + cc];
#pragma unroll
    for (int i = 0; i < 9; i++) w9[cc][i] = dww[(c4 + cc) * 9 + i];
  }
  const u16* ib = cin + (size_t)bimg * S1 * 256;
  float act[3][3][4];
#pragma unroll
  for (int pp = 0; pp < 16; pp++) {
    int p = wave * 16 + pp;
    int s = m0 + p - bimg * S1;
    int oh = s / 112, ow = s - oh * 112;
    if (pp == 0 || ow == 0) {
      LD_COL(oh, ow - 1, (pp + 0) % 3);
      LD_COL(oh, ow,     (pp + 1) % 3);
      LD_COL(oh, ow + 1, (pp + 2) % 3);
    } else {
      LD_COL(oh, ow + 1, (pp + 2) % 3);
    }
    float a0 = 0.f, a1 = 0.f, a2 = 0.f, a3 = 0.f;
#pragma unroll
    for (int dr = 0; dr < 3; dr++)
#pragma unroll
      for (int dc = 0; dc < 3; dc++) {
        const int sl = (pp + dc) % 3;
        const int wi = dr * 3 + dc;
        a0 = fmaf(w9[0][wi], act[dr][sl][0], a0);
        a1 = fmaf(w9[1][wi], act[dr][sl][1], a1);
        a2 = fmaf(w9[2][wi], act[dr][sl][2], a2);
        a3 = fmaf(w9[3][wi], act[dr][sl][3], a3);
      }
    union { u16 h[4]; uint2 v; } pk;
    pk.h[0] = f2bf(a0); pk.h[1] = f2bf(a1);
    pk.h[2] = f2bf(a2); pk.h[3] = f2bf(a3);
    *(uint2*)(out + (size_t)(m0 + p) * 256 + c4) = pk.v;
  }
}

// ---------------- streaming pw GEMM (big-ws path) ----------------
// N-split gridDim.y=2, nt=4, 3 waves/SIMD.
__global__ __launch_bounds__(256, 3) void k_pws(const u16* __restrict__ A,
    const u16* __restrict__ bwb, float* __restrict__ partials,
    const float* __restrict__ bn2p, int pass) {
  __shared__ u16 ash[64 * 256];
  int tid = threadIdx.x;
  int wave = tid >> 6, lane = tid & 63;
  int m0 = blockIdx.x * 64;
  {
    const char* gb = (const char*)(A + (size_t)m0 * 256);
    char* lb = (char*)ash;
#pragma unroll
    for (int i = 0; i < 8; i++) {
      int L = wave * 8192 + i * 1024 + lane * 16;
      int p = L >> 9;
      int gp = (L >> 4) & 31;
      int g = gp ^ (p & 7);
      uint4 v = *(const uint4*)(gb + (size_t)p * 512 + g * 16);
      *(uint4*)(lb + L) = v;
    }
  }
  __syncthreads();

  int quad = lane >> 4;
  int lr = lane & 15;
  int nbase = blockIdx.y * 256 + wave * 64;
  const char* ashb = (const char*)ash;
  f32x4 acc[4][4];
#pragma unroll
  for (int mt = 0; mt < 4; mt++)
#pragma unroll
    for (int nt = 0; nt < 4; nt++) acc[mt][nt] = (f32x4){0.f, 0.f, 0.f, 0.f};

#pragma unroll
  for (int ch = 0; ch < 8; ch++) {
    bf16x8 af[4];
#pragma unroll
    for (int mt = 0; mt < 4; mt++) {
      int row = mt * 16 + lr;
      int g = (ch * 4 + quad) ^ (row & 7);
      af[mt] = *(const bf16x8*)(ashb + row * 512 + g * 16);
    }
    bf16x8 bfr[4];
#pragma unroll
    for (int nt = 0; nt < 4; nt++)
      bfr[nt] = *(const bf16x8*)(bwb + (size_t)(nbase + nt * 16 + lr) * 256 + ch * 32 + quad * 8);
#pragma unroll
    for (int mt = 0; mt < 4; mt++)
#pragma unroll
      for (int nt = 0; nt < 4; nt++)
        acc[mt][nt] = __builtin_amdgcn_mfma_f32_16x16x32_bf16(af[mt], bfr[nt], acc[mt][nt], 0, 0, 0);
  }

  if (pass == 0) {
#pragma unroll
    for (int nt = 0; nt < 4; nt++) {
      float s = 0.f, q = 0.f;
#pragma unroll
      for (int mt = 0; mt < 4; mt++)
#pragma unroll
        for (int r = 0; r < 4; r++) {
          float v = acc[mt][nt][r];
          s += v; q = fmaf(v, v, q);
        }
      s += __shfl_xor(s, 16); s += __shfl_xor(s, 32);
      q += __shfl_xor(q, 16); q += __shfl_xor(q, 32);
      if (lane < 16) {
        int n = nbase + nt * 16 + lane;
        partials[(size_t)blockIdx.x * 1024 + n] = s;
        partials[(size_t)blockIdx.x * 1024 + 512 + n] = q;
      }
    }
  } else {
#pragma unroll
    for (int nt = 0; nt < 4; nt++) {
      int n = nbase + nt * 16 + lr;
      float scn = bn2p[n], shn = bn2p[512 + n];
      float s = 0.f;
#pragma unroll
      for (int mt = 0; mt < 4; mt++)
#pragma unroll
        for (int r = 0; r < 4; r++)
          s += fmaxf(fmaf(acc[mt][nt][r], scn, shn), 0.f);
      s += __shfl_xor(s, 16); s += __shfl_xor(s, 32);
      if (lane < 16)
        partials[(size_t)blockIdx.x * 512 + n] = s;
    }
  }
}

// ---------------- fused dw+pw (small-ws fallback) ----------------
__global__ __launch_bounds__(256, 2) void k_pwpass(
    const u16* __restrict__ conv1out, const float* __restrict__ bn1p,
    const float* __restrict__ dww, const u16* __restrict__ bwb,
    float* __restrict__ partials, const float* __restrict__ bn2p, int pass) {
  __shared__ u16 ash[64 * AP];
  int tid = threadIdx.x;
  int wave = tid >> 6;
  int lane = tid & 63;
  int m0 = blockIdx.x * 64;
  int bimg = blockIdx.x / 196;
  {
    int c4 = lane * 4;
    float sc[4], sh[4], w9[4][9];
#pragma unroll
    for (int cc = 0; cc < 4; cc++) {
      sc[cc] = bn1p[c4 + cc];
      sh[cc] = bn1p[256 + c4 + cc];
#pragma unroll
      for (int i = 0; i < 9; i++) w9[cc][i] = dww[(c4 + cc) * 9 + i];
    }
    const u16* ib = conv1out + (size_t)bimg * S1 * 256;
    float act[3][3][4];
#pragma unroll
    for (int pp = 0; pp < 16; pp++) {
      int p = wave * 16 + pp;
      int s = m0 + p - bimg * S1;
      int oh = s / 112, ow = s - oh * 112;
      if (pp == 0 || ow == 0) {
        LD_COL(oh, ow - 1, (pp + 0) % 3);
        LD_COL(oh, ow,     (pp + 1) % 3);
        LD_COL(oh, ow + 1, (pp + 2) % 3);
      } else {
        LD_COL(oh, ow + 1, (pp + 2) % 3);
      }
      float a0 = 0.f, a1 = 0.f, a2 = 0.f, a3 = 0.f;
#pragma unroll
      for (int dr = 0; dr < 3; dr++)
#pragma unroll
        for (int dc = 0; dc < 3; dc++) {
          const int sl = (pp + dc) % 3;
          const int wi = dr * 3 + dc;
          a0 = fmaf(w9[0][wi], act[dr][sl][0], a0);
          a1 = fmaf(w9[1][wi], act[dr][sl][1], a1);
          a2 = fmaf(w9[2][wi], act[dr][sl][2], a2);
          a3 = fmaf(w9[3][wi], act[dr][sl][3], a3);
        }
      union { u16 h[4]; uint2 v; } pk;
      pk.h[0] = f2bf(a0); pk.h[1] = f2bf(a1);
      pk.h[2] = f2bf(a2); pk.h[3] = f2bf(a3);
      *(uint2*)(&ash[p * AP + c4]) = pk.v;
    }
  }
  __syncthreads();
  int quad = lane >> 4;
  int lr = lane & 15;
  int nbase = wave * 128;
  f32x4 acc[4][8];
#pragma unroll
  for (int mt = 0; mt < 4; mt++)
#pragma unroll
    for (int nt = 0; nt < 8; nt++) acc[mt][nt] = (f32x4){0.f, 0.f, 0.f, 0.f};
  for (int kk = 0; kk < 256; kk += 32) {
    bf16x8 af[4];
#pragma unroll
    for (int mt = 0; mt < 4; mt++)
      af[mt] = *(const bf16x8*)(&ash[(mt * 16 + lr) * AP + kk + quad * 8]);
    bf16x8 bfr[8];
#pragma unroll
    for (int nt = 0; nt < 8; nt++)
      bfr[nt] = *(const bf16x8*)(bwb + (size_t)(nbase + nt * 16 + lr) * 256 + kk + quad * 8);
#pragma unroll
    for (int mt = 0; mt < 4; mt++)
#pragma unroll
      for (int nt = 0; nt < 8; nt++)
        acc[mt][nt] = __builtin_amdgcn_mfma_f32_16x16x32_bf16(af[mt], bfr[nt], acc[mt][nt], 0, 0, 0);
  }
  if (pass == 0) {
#pragma unroll
    for (int nt = 0; nt < 8; nt++) {
      float s = 0.f, q = 0.f;
#pragma unroll
      for (int mt = 0; mt < 4; mt++)
#pragma unroll
        for (int r = 0; r < 4; r++) {
          float v = acc[mt][nt][r];
          s += v; q = fmaf(v, v, q);
        }
      s += __shfl_xor(s, 16); s += __shfl_xor(s, 32);
      q += __shfl_xor(q, 16); q += __shfl_xor(q, 32);
      if (lane < 16) {
        int n = nbase + nt * 16 + lane;
        partials[(size_t)blockIdx.x * 1024 + n] = s;
        partials[(size_t)blockIdx.x * 1024 + 512 + n] = q;
      }
    }
  } else {
#pragma unroll
    for (int nt = 0; nt < 8; nt++) {
      int n = nbase + nt * 16 + lr;
      float scn = bn2p[n], shn = bn2p[512 + n];
      float s = 0.f;
#pragma unroll
      for (int mt = 0; mt < 4; mt++)
#pragma unroll
        for (int r = 0; r < 4; r++)
          s += fmaxf(fmaf(acc[mt][nt][r], scn, shn), 0.f);
      s += __shfl_xor(s, 16); s += __shfl_xor(s, 32);
      if (lane < 16)
        partials[(size_t)blockIdx.x * 512 + n] = s;
    }
  }
}

// ---------------- reductions ----------------
__global__ __launch_bounds__(256) void k_red1(const float* __restrict__ P, float* __restrict__ P2) {
  int blk = blockIdx.x;
  int t = threadIdx.x;
  float4 s = {0.f, 0.f, 0.f, 0.f};
  for (int r = 0; r < 49; r++) {
    float4 v = *(const float4*)(P + ((size_t)(blk * 49 + r)) * 1024 + t * 4);
    s.x += v.x; s.y += v.y; s.z += v.z; s.w += v.w;
  }
  *(float4*)(P2 + (size_t)blk * 1024 + t * 4) = s;
}

__global__ void k_red_bn2(const float* __restrict__ P2, const float* __restrict__ g,
                          const float* __restrict__ bb, float* __restrict__ par) {
  int c = blockIdx.x * 256 + threadIdx.x;
  float s = 0.f, q = 0.f;
  for (int i = 0; i < 64; i++) {
    s += P2[(size_t)i * 1024 + c];
    q += P2[(size_t)i * 1024 + 512 + c];
  }
  float m = s * (1.f / (float)NSTAT);
  float v = q * (1.f / (float)NSTAT) - m * m;
  float sc = g[c] * rsqrtf(v + EPS);
  par[c] = sc;
  par[512 + c] = bb[c] - m * sc;
}

__global__ void k_red_y(const float* __restrict__ P, float* __restrict__ yb) {
  int idx = blockIdx.x * 256 + threadIdx.x;
  int b = idx >> 9, c = idx & 511;
  float s = 0.f;
  for (int i = 0; i < 196; i++) s += P[(size_t)(b * 196 + i) * 512 + c];
  yb[idx] = s;
}

// ---------------- per-batch SE + enc_fc + ctx ----------------
__global__ __launch_bounds__(256) void k_se(const float* __restrict__ y,
    const float* __restrict__ se1, const float* __restrict__ se2,
    const float* __restrict__ encw, const float* __restrict__ encb,
    const float* __restrict__ vw, float* __restrict__ ctxb) {
  int b = blockIdx.x;
  int t = threadIdx.x;
  __shared__ __align__(16) float ybar[512];
  __shared__ __align__(16) float uu[128];
  __shared__ __align__(16) float ff[512];
  __shared__ __align__(16) float feats[512];
  for (int i = t; i < 512; i += 256) ybar[i] = y[b * 512 + i] * (1.f / 12544.f);
  __syncthreads();
  if (t < 128) {
    const float4* wr = (const float4*)(se1 + t * 512);
    const float4* xv = (const float4*)ybar;
    float a = 0.f;
    for (int k = 0; k < 128; k++) {
      float4 w4 = wr[k], x4 = xv[k];
      a = fmaf(w4.x, x4.x, a); a = fmaf(w4.y, x4.y, a);
      a = fmaf(w4.z, x4.z, a); a = fmaf(w4.w, x4.w, a);
    }
    uu[t] = fmaxf(a, 0.f);
  }
  __syncthreads();
  for (int c = t; c < 512; c += 256) {
    const float4* wr = (const float4*)(se2 + c * 128);
    const float4* xv = (const float4*)uu;
    float a = 0.f;
    for (int k = 0; k < 32; k++) {
      float4 w4 = wr[k], x4 = xv[k];
      a = fmaf(w4.x, x4.x, a); a = fmaf(w4.y, x4.y, a);
      a = fmaf(w4.z, x4.z, a); a = fmaf(w4.w, x4.w, a);
    }
    ff[c] = ybar[c] * sigm(a);
  }
  __syncthreads();
  for (int c = t; c < 512; c += 256) {
    const float4* wr = (const float4*)(encw + (size_t)c * 512);
    const float4* xv = (const float4*)ff;
    float a = encb[c];
    for (int k = 0; k < 128; k++) {
      float4 w4 = wr[k], x4 = xv[k];
      a = fmaf(w4.x, x4.x, a); a = fmaf(w4.y, x4.y, a);
      a = fmaf(w4.z, x4.z, a); a = fmaf(w4.w, x4.w, a);
    }
    feats[c] = a;
  }
  __syncthreads();
  for (int c = t; c < 512; c += 256) {
    const float4* wr = (const float4*)(vw + (size_t)c * 512);
    const float4* xv = (const float4*)feats;
    float a = 0.f;
    for (int k = 0; k < 128; k++) {
      float4 w4 = wr[k], x4 = xv[k];
      a = fmaf(w4.x, x4.x, a); a = fmaf(w4.y, x4.y, a);
      a = fmaf(w4.z, x4.z, a); a = fmaf(w4.w, x4.w, a);
    }
    ctxb[b * 512 + c] = a;
  }
}

// ---------------- gi split: ctx half once (K=512), emb half per step ----------------
// Round-17: k_gi3 at 117us was a dependent-load latency chain (VALUBusy 22%,
// Occ 66%, unroll-2 left ~2 emb load-pairs in flight vs ~400cy L2/L3 latency).
// Fix: group b-loop by 8 — issue 8 token loads, then 16 independent float4
// embed loads (8 pairs in flight), then 8 FMA+shfl-reduce chains. +64 VGPR
// (static indexing) on a 20-VGPR kernel: still >=5 waves/SIMD.
__global__ __launch_bounds__(256) void k_gctx(const float* __restrict__ ctxb,
    const float* __restrict__ wih, const float* __restrict__ bih, float* __restrict__ gictx) {
  int lb = threadIdx.x >> 4;
  int lj = threadIdx.x & 15;
  int j = blockIdx.x * 16 + lj;
  const float4* wr = (const float4*)(wih + (size_t)j * 1024 + 512);
  const float4* xv = (const float4*)(ctxb + lb * 512);
  float a = bih[j];
#pragma unroll 4
  for (int k = 0; k < 128; k++) {
    float4 w4 = wr[k], x4 = xv[k];
    a = fmaf(w4.x, x4.x, a); a = fmaf(w4.y, x4.y, a);
    a = fmaf(w4.z, x4.z, a); a = fmaf(w4.w, x4.w, a);
  }
  gictx[lb * 1536 + j] = a;
}

__global__ __launch_bounds__(256) void k_gi3(const int* __restrict__ caps,
    const float* __restrict__ embed, const float* __restrict__ wih,
    const float* __restrict__ gictx, float* __restrict__ gi) {
  int wave = threadIdx.x >> 6, lane = threadIdx.x & 63;
  int j = blockIdx.x * 4 + wave;        // 384 blocks.x x 4 waves = 1536 j
  int t0 = blockIdx.y * 8;              // 4 blocks.y x 8 steps = 32 t
  const float4* wr = (const float4*)(wih + (size_t)j * 1024 + lane * 8);
  float4 w0 = wr[0], w1 = wr[1];        // wih[j][lane*8 .. +8], coalesced, reg-resident
  for (int tt = t0; tt < t0 + 8; tt++) {
#pragma unroll
    for (int bb = 0; bb < 16; bb += 8) {
      float4 x0[8], x1[8];
#pragma unroll
      for (int u = 0; u < 8; u++) {
        int tok = caps[(bb + u) * 33 + tt];
        const float4* xv = (const float4*)(embed + (size_t)tok * 512 + lane * 8);
        x0[u] = xv[0]; x1[u] = xv[1];
      }
#pragma unroll
      for (int u = 0; u < 8; u++) {
        float a = w0.x * x0[u].x;
        a = fmaf(w0.y, x0[u].y, a); a = fmaf(w0.z, x0[u].z, a); a = fmaf(w0.w, x0[u].w, a);
        a = fmaf(w1.x, x1[u].x, a); a = fmaf(w1.y, x1[u].y, a);
        a = fmaf(w1.z, x1[u].z, a); a = fmaf(w1.w, x1[u].w, a);
#pragma unroll
        for (int m = 1; m < 64; m <<= 1) a += __shfl_xor(a, m);
        if (lane == 0)
          gi[((size_t)tt * 16 + bb + u) * 1536 + j] = a + gictx[(bb + u) * 1536 + j];
      }
    }
  }
}

// ---------------- GRU single step (launched 32x; kernel boundary = barrier) ----------------
__global__ __launch_bounds__(192) void k_gru_step(const float* __restrict__ whh,
    const float* __restrict__ bhh, const float* __restrict__ gi_t,
    const float* __restrict__ h_in, float* __restrict__ h_out) {
  int g = blockIdx.x;
  int tid = threadIdx.x;
  int s = tid / 24;          // 0..7
  int r = tid - s * 24;      // 0..23
  int gate = r >> 3, lj = r & 7;
  int jj = g * 8 + lj;
  int R = gate * 512 + jj;
  float4 w[16];
  {
    const float4* wp = (const float4*)(whh + (size_t)R * 512 + s * 64);
#pragma unroll
    for (int i = 0; i < 16; i++) w[i] = wp[i];
  }
  __shared__ __align__(16) float hs[16][512];
  __shared__ float pr[8][24][16];   // [seg][row][batch]

  // stage h_t (plain vector loads; coherent via kernel boundary)
  {
    const float4* hp = (const float4*)h_in;
    float4* hd = (float4*)&hs[0][0];
    for (int i = tid; i < 2048; i += 192) hd[i] = hp[i];
  }
  __syncthreads();
  // per-thread partial dots: 16 batches x 64-wide segment
#pragma unroll
  for (int b = 0; b < 16; b++) {
    const float4* hv = (const float4*)&hs[b][s * 64];
    float a = 0.f;
#pragma unroll
    for (int k = 0; k < 16; k++) {
      float4 w4 = w[k], h4 = hv[k];
      a = fmaf(w4.x, h4.x, a); a = fmaf(w4.y, h4.y, a);
      a = fmaf(w4.z, h4.z, a); a = fmaf(w4.w, h4.w, a);
    }
    pr[s][r][b] = a;
  }
  __syncthreads();
  // combine gates + h update: threads 0..127, b=tid>>3, jl=tid&7
  if (tid < 128) {
    int b = tid >> 3, jl = tid & 7;
    int j = g * 8 + jl;
    float gh[3];
#pragma unroll
    for (int gg = 0; gg < 3; gg++) {
      int rr = gg * 8 + jl;
      float sum = bhh[gg * 512 + j];
#pragma unroll
      for (int ss = 0; ss < 8; ss++) sum += pr[ss][rr][b];
      gh[gg] = sum;
    }
    const float* gib = gi_t + (size_t)b * 1536;
    float rg = sigm(gib[j] + gh[0]);
    float z  = sigm(gib[j + 512] + gh[1]);
    float n  = tanhf(gib[j + 1024] + rg * gh[2]);
    float hp = hs[b][j];
    h_out[b * 512 + j] = (1.f - z) * n + z * hp;
  }
}

// ---------------- logits GEMM (bf16 MFMA) ----------------
__global__ __launch_bounds__(256) void k_fc(const float* __restrict__ A,
    const u16* __restrict__ Bwb, const float* __restrict__ bias, float* __restrict__ out) {
  __shared__ u16 ash[128 * 136];
  int tid = threadIdx.x;
  int wave = tid >> 6;
  int lane = tid & 63;
  int quad = lane >> 4;
  int lr = lane & 15;
  int N0 = blockIdx.x * 256;
  int M0 = blockIdx.y * 128;
  f32x4 acc[8][4];
#pragma unroll
  for (int mf = 0; mf < 8; mf++)
#pragma unroll
    for (int nf = 0; nf < 4; nf++) acc[mf][nf] = (f32x4){0.f, 0.f, 0.f, 0.f};
  int arow = tid >> 1;
  int acol = (tid & 1) * 64;
  for (int kc = 0; kc < 512; kc += 128) {
#pragma unroll
    for (int j = 0; j < 16; j++) {
      float4 v = *(const float4*)(A + (size_t)(M0 + arow) * 512 + kc + acol + j * 4);
      union { u16 h[4]; uint2 u; } pk;
      pk.h[0] = f2bf(v.x); pk.h[1] = f2bf(v.y); pk.h[2] = f2bf(v.z); pk.h[3] = f2bf(v.w);
      *(uint2*)(&ash[arow * 136 + acol + j * 4]) = pk.u;
    }
    __syncthreads();
#pragma unroll
    for (int ks = 0; ks < 128; ks += 32) {
      bf16x8 af[8];
#pragma unroll
      for (int mf = 0; mf < 8; mf++)
        af[mf] = *(const bf16x8*)(&ash[(mf * 16 + lr) * 136 + ks + quad * 8]);
      bf16x8 bf[4];
#pragma unroll
      for (int nf = 0; nf < 4; nf++) {
        int n = N0 + wave * 64 + nf * 16 + lr;
        bf[nf] = *(const bf16x8*)(Bwb + (size_t)n * 512 + kc + ks + quad * 8);
      }
#pragma unroll
      for (int mf = 0; mf < 8; mf++)
#pragma unroll
        for (int nf = 0; nf < 4; nf++)
          acc[mf][nf] = __builtin_amdgcn_mfma_f32_16x16x32_bf16(af[mf], bf[nf], acc[mf][nf], 0, 0, 0);
    }
    __syncthreads();
  }
#pragma unroll
  for (int nf = 0; nf < 4; nf++) {
    int j = N0 + wave * 64 + nf * 16 + lr;
    float bv = bias[j];
#pragma unroll
    for (int mf = 0; mf < 8; mf++)
#pragma unroll
      for (int r = 0; r < 4; r++) {
        int m = M0 + mf * 16 + quad * 4 + r;   // m = t*16 + b
        int orow = (m & 15) * 32 + (m >> 4);   // out row = b*32 + t
        out[(size_t)orow * 32000 + j] = acc[mf][nf][r] + bv;
      }
  }
}

extern "C" void kernel_launch(void* const* d_in, const int* in_sizes, int n_in,
                              void* d_out, int out_size, void* d_ws, size_t ws_size,
                              hipStream_t stream) {
  const float* images  = (const float*)d_in[0];
  const int*   caps    = (const int*)d_in[1];
  const float* conv1_w = (const float*)d_in[2];
  const float* bn1_g   = (const float*)d_in[3];
  const float* bn1_b   = (const float*)d_in[4];
  const float* dw_w    = (const float*)d_in[5];
  const float* pw_w    = (const float*)d_in[6];
  const float* bn2_g   = (const float*)d_in[7];
  const float* bn2_b   = (const float*)d_in[8];
  const float* se1     = (const float*)d_in[9];
  const float* se2     = (const float*)d_in[10];
  const float* encw    = (const float*)d_in[11];
  const float* encb    = (const float*)d_in[12];
  const float* embed   = (const float*)d_in[13];
  const float* vw      = (const float*)d_in[16];
  const float* wih     = (const float*)d_in[17];
  const float* whh     = (const float*)d_in[18];
  const float* bih     = (const float*)d_in[19];
  const float* bhh     = (const float*)d_in[20];
  const float* fcw     = (const float*)d_in[21];
  const float* fcb     = (const float*)d_in[22];
  float* out = (float*)d_out;

  const bool big = ws_size >= (size_t)230 * 1000 * 1000;

  char* ws = (char*)d_ws;
  size_t off = 0;
  auto alloc = [&](size_t bytes) {
    void* p = ws + off;
    off = (off + bytes + 255) & ~(size_t)255;
    return p;
  };
  u16* conv1out = (u16*)alloc((size_t)51380224 * 2);
  u16* fcwb     = (u16*)conv1out;                       // alias (dead after dw/pwpass)
  u16* dwout    = big ? (u16*)alloc((size_t)51380224 * 2) : (u16*)nullptr;
  u16* bwb      = (u16*)alloc((size_t)131072 * 2);
  float* partials = (float*)alloc((size_t)3136 * 1024 * 4);
  float* p2     = (float*)alloc((size_t)64 * 1024 * 4);
  float* stats1 = (float*)alloc(512 * 4);
  float* h_all  = (float*)alloc((size_t)33 * 8192 * 4);
  float* bn1p   = (float*)alloc(512 * 4);
  float* bn2p   = (float*)alloc(1024 * 4);
  float* yb     = (float*)alloc(8192 * 4);
  float* ctxb   = (float*)alloc(8192 * 4);
  float* gictx  = (float*)alloc((size_t)16 * 1536 * 4);
  float* gi     = (float*)alloc((size_t)32 * 16 * 1536 * 4);
  (void)in_sizes; (void)n_in; (void)out_size;

  hipMemsetAsync(stats1, 0, 512 * 4, stream);
  hipMemsetAsync(h_all, 0, 8192 * 4, stream);   // h0 = 0

  k_conv1<<<896, 256, 0, stream>>>(images, conv1_w, conv1out, stats1);
  k_bnfin<<<1, 256, 0, stream>>>(stats1, bn1_g, bn1_b, bn1p, 256, 1.f / (float)NSTAT);
  k_cvt4<<<128, 256, 0, stream>>>(pw_w, bwb, 32768);

  if (big) {
    k_dws<<<3136, 256, 0, stream>>>(conv1out, bn1p, dw_w, dwout);
    k_cvt4<<<16000, 256, 0, stream>>>(fcw, fcwb, 4096000);
    dim3 gpw(3136, 2);
    k_pws<<<gpw, 256, 0, stream>>>(dwout, bwb, partials, bn2p, 0);
    k_red1<<<64, 256, 0, stream>>>(partials, p2);
    k_red_bn2<<<2, 256, 0, stream>>>(p2, bn2_g, bn2_b, bn2p);
    k_pws<<<gpw, 256, 0, stream>>>(dwout, bwb, partials, bn2p, 1);
  } else {
    k_pwpass<<<3136, 256, 0, stream>>>(conv1out, bn1p, dw_w, bwb, partials, bn2p, 0);
    k_red1<<<64, 256, 0, stream>>>(partials, p2);
    k_red_bn2<<<2, 256, 0, stream>>>(p2, bn2_g, bn2_b, bn2p);
    k_pwpass<<<3136, 256, 0, stream>>>(conv1out, bn1p, dw_w, bwb, partials, bn2p, 1);
    k_cvt4<<<16000, 256, 0, stream>>>(fcw, fcwb, 4096000);
  }
  k_red_y<<<32, 256, 0, stream>>>(partials, yb);
  k_se<<<16, 256, 0, stream>>>(yb, se1, se2, encw, encb, vw, ctxb);
  k_gctx<<<96, 256, 0, stream>>>(ctxb, wih, bih, gictx);
  dim3 ggi3(384, 4);
  k_gi3<<<ggi3, 256, 0, stream>>>(caps, embed, wih, gictx, gi);
  for (int t = 0; t < 32; t++)
    k_gru_step<<<64, 192, 0, stream>>>(whh, bhh, gi + (size_t)t * 16 * 1536,
                                       h_all + (size_t)t * 8192, h_all + (size_t)(t + 1) * 8192);
  dim3 gfc(125, 4);
  k_fc<<<gfc, 256, 0, stream>>>(h_all + 8192, fcwb, fcb, out);
}

// Round 20
// 1236.434 us; speedup vs baseline: 1.0295x; 1.0295x over previous
//
#include <hip/hip_runtime.h>

typedef unsigned int u32;
typedef unsigned short u16;
typedef unsigned long long u64;
typedef short bf16x8 __attribute__((ext_vector_type(8)));
typedef float f32x4 __attribute__((ext_vector_type(4)));

#define S1 12544      // 112*112
#define NSTAT 200704  // 16*112*112
#define EPS 1e-5f
#define AP 264        // padded A-tile row length (fused path)

__device__ __forceinline__ u16 f2bf(float f) {
  union { float f; u32 u; } x; x.f = f;
  u32 r = x.u + 0x7fffu + ((x.u >> 16) & 1u);
  return (u16)(r >> 16);
}
__device__ __forceinline__ void bf2x2(u32 u, float& lo, float& hi) {
  union { u32 u; float f; } a, b;
  a.u = u << 16; b.u = u & 0xffff0000u;
  lo = a.f; hi = b.f;
}
__device__ __forceinline__ float sigm(float x) { return 1.f / (1.f + expf(-x)); }

// ---------------- conv1 (3->256, 3x3, stride2, pad1) + bn1 stats ----------------
#define CW 225
__global__ __launch_bounds__(256) void k_conv1(const float* __restrict__ img,
    const float* __restrict__ w, u16* __restrict__ out, float* __restrict__ stats) {
  int blk = blockIdx.x;
  int b = blk / 56, strip = blk - b * 56;
  int r0 = strip * 2;
  int c = threadIdx.x;
  __shared__ float simg[3 * 5 * CW];
  const float* ib = img + (size_t)b * 3 * 224 * 224;
  for (int i = c; i < 3 * 5 * CW; i += 256) {
    int ch = i / (5 * CW);
    int rem = i - ch * (5 * CW);
    int lr = rem / CW;
    int col = rem - lr * CW;
    int ih = 2 * r0 - 1 + lr;
    int iw = col - 1;
    float v = 0.f;
    if (ih >= 0 && ih < 224 && iw >= 0 && iw < 224) v = ib[((size_t)ch * 224 + ih) * 224 + iw];
    simg[i] = v;
  }
  float wr[27];
#pragma unroll
  for (int i = 0; i < 27; i++) wr[i] = w[c * 27 + i];
  __syncthreads();
  float s = 0.f, q = 0.f;
  for (int orow = 0; orow < 2; orow++) {
    int oh = r0 + orow;
    for (int ow = 0; ow < 112; ow++) {
      float acc = 0.f;
#pragma unroll
      for (int ch = 0; ch < 3; ch++)
#pragma unroll
        for (int dr = 0; dr < 3; dr++) {
          const float* rp = &simg[(ch * 5 + 2 * orow + dr) * CW + 2 * ow];
          acc = fmaf(wr[(ch * 3 + dr) * 3 + 0], rp[0], acc);
          acc = fmaf(wr[(ch * 3 + dr) * 3 + 1], rp[1], acc);
          acc = fmaf(wr[(ch * 3 + dr) * 3 + 2], rp[2], acc);
        }
      s += acc; q = fmaf(acc, acc, q);
      out[((size_t)(b * 112 + oh) * 112 + ow) * 256 + c] = f2bf(acc);
    }
  }
  atomicAdd(&stats[c], s);
  atomicAdd(&stats[256 + c], q);
}

// ---------------- bn finalize ----------------
__global__ void k_bnfin(const float* __restrict__ stats, const float* __restrict__ g,
                        const float* __restrict__ bb, float* __restrict__ par, int C, float invN) {
  int c = blockIdx.x * 256 + threadIdx.x;
  if (c < C) {
    float m = stats[c] * invN;
    float v = stats[C + c] * invN - m * m;
    float sc = g[c] * rsqrtf(v + EPS);
    par[c] = sc;
    par[C + c] = bb[c] - m * sc;
  }
}

// ---------------- fp32 -> bf16 x4 ----------------
__global__ void k_cvt4(const float* __restrict__ w, u16* __restrict__ o, int n4) {
  int i = blockIdx.x * 256 + threadIdx.x;
  if (i < n4) {
    float4 v = ((const float4*)w)[i];
    union { u16 h[4]; uint2 u; } pk;
    pk.h[0] = f2bf(v.x); pk.h[1] = f2bf(v.y); pk.h[2] = f2bf(v.z); pk.h[3] = f2bf(v.w);
    ((uint2*)o)[i] = pk.u;
  }
}

// ---- shared sliding-window dw macro (uses locals: ib, c4, sc, sh, act) ----
#define LD_COL(ohv, iwv, slot) do {                                          \
    int _oh = (ohv), _iw = (iwv);                                            \
  _Pragma("unroll")                                                          \
    for (int _dr = 0; _dr < 3; _dr++) {                                      \
      int _ih = _oh - 1 + _dr;                                               \
      float _x0 = 0.f, _x1 = 0.f, _x2 = 0.f, _x3 = 0.f;                      \
      if (_ih >= 0 && _ih < 112 && _iw >= 0 && _iw < 112) {                  \
        uint2 _v = *(const uint2*)(ib + ((size_t)(_ih * 112 + _iw)) * 256 + c4); \
        float _t0, _t1, _t2, _t3;                                            \
        bf2x2(_v.x, _t0, _t1); bf2x2(_v.y, _t2, _t3);                        \
        _x0 = fmaxf(fmaf(_t0, sc[0], sh[0]), 0.f);                           \
        _x1 = fmaxf(fmaf(_t1, sc[1], sh[1]), 0.f);                           \
        _x2 = fmaxf(fmaf(_t2, sc[2], sh[2]), 0.f);                           \
        _x3 = fmaxf(fmaf(_t3, sc[3], sh[3]), 0.f);                           \
      }                                                                      \
      act[_dr][slot][0] = _x0; act[_dr][slot][1] = _x1;                      \
      act[_dr][slot][2] = _x2; act[_dr][slot][3] = _x3;                      \
    }                                                                      \
  } while (0)

// ---------------- standalone dw kernel (big-ws path): conv1out -> dwout bf16 ----------------
__global__ __launch_bounds__(256) void k_dws(const u16* __restrict__ cin,
    const float* __restrict__ bn1p, const float* __restrict__ dww, u16* __restrict__ out) {
  int tid = threadIdx.x;
  int wave = tid >> 6, lane = tid & 63;
  int c4 = lane * 4;
  int m0 = blockIdx.x * 64;
  int bimg = blockIdx.x / 196;
  float sc[4], sh[4], w9[4][9];
#pragma unroll
  for (int cc = 0; cc < 4; cc++) {
    sc[cc] = bn1p[c4 + cc];
    sh[cc] = bn1p[256 + c4 + cc];
#pragma unroll
    for (int i = 0; i < 9; i++) w9[cc][i] = dww[(c4 + cc) * 9 + i];
  }
  const u16* ib = cin + (size_t)bimg * S1 * 256;
  float act[3][3][4];
#pragma unroll
  for (int pp = 0; pp < 16; pp++) {
    int p = wave * 16 + pp;
    int s = m0 + p - bimg * S1;
    int oh = s / 112, ow = s - oh * 112;
    if (pp == 0 || ow == 0) {
      LD_COL(oh, ow - 1, (pp + 0) % 3);
      LD_COL(oh, ow,     (pp + 1) % 3);
      LD_COL(oh, ow + 1, (pp + 2) % 3);
    } else {
      LD_COL(oh, ow + 1, (pp + 2) % 3);
    }
    float a0 = 0.f, a1 = 0.f, a2 = 0.f, a3 = 0.f;
#pragma unroll
    for (int dr = 0; dr < 3; dr++)
#pragma unroll
      for (int dc = 0; dc < 3; dc++) {
        const int sl = (pp + dc) % 3;
        const int wi = dr * 3 + dc;
        a0 = fmaf(w9[0][wi], act[dr][sl][0], a0);
        a1 = fmaf(w9[1][wi], act[dr][sl][1], a1);
        a2 = fmaf(w9[2][wi], act[dr][sl][2], a2);
        a3 = fmaf(w9[3][wi], act[dr][sl][3], a3);
      }
    union { u16 h[4]; uint2 v; } pk;
    pk.h[0] = f2bf(a0); pk.h[1] = f2bf(a1);
    pk.h[2] = f2bf(a2); pk.h[3] = f2bf(a3);
    *(uint2*)(out + (size_t)(m0 + p) * 256 + c4) = pk.v;
  }
}

// ---------------- streaming pw GEMM (big-ws path) ----------------
// N-split gridDim.y=2, nt=4, 3 waves/SIMD.
__global__ __launch_bounds__(256, 3) void k_pws(const u16* __restrict__ A,
    const u16* __restrict__ bwb, float* __restrict__ partials,
    const float* __restrict__ bn2p, int pass) {
  __shared__ u16 ash[64 * 256];
  int tid = threadIdx.x;
  int wave = tid >> 6, lane = tid & 63;
  int m0 = blockIdx.x * 64;
  {
    const char* gb = (const char*)(A + (size_t)m0 * 256);
    char* lb = (char*)ash;
#pragma unroll
    for (int i = 0; i < 8; i++) {
      int L = wave * 8192 + i * 1024 + lane * 16;
      int p = L >> 9;
      int gp = (L >> 4) & 31;
      int g = gp ^ (p & 7);
      uint4 v = *(const uint4*)(gb + (size_t)p * 512 + g * 16);
      *(uint4*)(lb + L) = v;
    }
  }
  __syncthreads();

  int quad = lane >> 4;
  int lr = lane & 15;
  int nbase = blockIdx.y * 256 + wave * 64;
  const char* ashb = (const char*)ash;
  f32x4 acc[4][4];
#pragma unroll
  for (int mt = 0; mt < 4; mt++)
#pragma unroll
    for (int nt = 0; nt < 4; nt++) acc[mt][nt] = (f32x4){0.f, 0.f, 0.f, 0.f};

#pragma unroll
  for (int ch = 0; ch < 8; ch++) {
    bf16x8 af[4];
#pragma unroll
    for (int mt = 0; mt < 4; mt++) {
      int row = mt * 16 + lr;
      int g = (ch * 4 + quad) ^ (row & 7);
      af[mt] = *(const bf16x8*)(ashb + row * 512 + g * 16);
    }
    bf16x8 bfr[4];
#pragma unroll
    for (int nt = 0; nt < 4; nt++)
      bfr[nt] = *(const bf16x8*)(bwb + (size_t)(nbase + nt * 16 + lr) * 256 + ch * 32 + quad * 8);
#pragma unroll
    for (int mt = 0; mt < 4; mt++)
#pragma unroll
      for (int nt = 0; nt < 4; nt++)
        acc[mt][nt] = __builtin_amdgcn_mfma_f32_16x16x32_bf16(af[mt], bfr[nt], acc[mt][nt], 0, 0, 0);
  }

  if (pass == 0) {
#pragma unroll
    for (int nt = 0; nt < 4; nt++) {
      float s = 0.f, q = 0.f;
#pragma unroll
      for (int mt = 0; mt < 4; mt++)
#pragma unroll
        for (int r = 0; r < 4; r++) {
          float v = acc[mt][nt][r];
          s += v; q = fmaf(v, v, q);
        }
      s += __shfl_xor(s, 16); s += __shfl_xor(s, 32);
      q += __shfl_xor(q, 16); q += __shfl_xor(q, 32);
      if (lane < 16) {
        int n = nbase + nt * 16 + lane;
        partials[(size_t)blockIdx.x * 1024 + n] = s;
        partials[(size_t)blockIdx.x * 1024 + 512 + n] = q;
      }
    }
  } else {
#pragma unroll
    for (int nt = 0; nt < 4; nt++) {
      int n = nbase + nt * 16 + lr;
      float scn = bn2p[n], shn = bn2p[512 + n];
      float s = 0.f;
#pragma unroll
      for (int mt = 0; mt < 4; mt++)
#pragma unroll
        for (int r = 0; r < 4; r++)
          s += fmaxf(fmaf(acc[mt][nt][r], scn, shn), 0.f);
      s += __shfl_xor(s, 16); s += __shfl_xor(s, 32);
      if (lane < 16)
        partials[(size_t)blockIdx.x * 512 + n] = s;
    }
  }
}

// ---------------- fused dw+pw (small-ws fallback) ----------------
__global__ __launch_bounds__(256, 2) void k_pwpass(
    const u16* __restrict__ conv1out, const float* __restrict__ bn1p,
    const float* __restrict__ dww, const u16* __restrict__ bwb,
    float* __restrict__ partials, const float* __restrict__ bn2p, int pass) {
  __shared__ u16 ash[64 * AP];
  int tid = threadIdx.x;
  int wave = tid >> 6;
  int lane = tid & 63;
  int m0 = blockIdx.x * 64;
  int bimg = blockIdx.x / 196;
  {
    int c4 = lane * 4;
    float sc[4], sh[4], w9[4][9];
#pragma unroll
    for (int cc = 0; cc < 4; cc++) {
      sc[cc] = bn1p[c4 + cc];
      sh[cc] = bn1p[256 + c4 + cc];
#pragma unroll
      for (int i = 0; i < 9; i++) w9[cc][i] = dww[(c4 + cc) * 9 + i];
    }
    const u16* ib = conv1out + (size_t)bimg * S1 * 256;
    float act[3][3][4];
#pragma unroll
    for (int pp = 0; pp < 16; pp++) {
      int p = wave * 16 + pp;
      int s = m0 + p - bimg * S1;
      int oh = s / 112, ow = s - oh * 112;
      if (pp == 0 || ow == 0) {
        LD_COL(oh, ow - 1, (pp + 0) % 3);
        LD_COL(oh, ow,     (pp + 1) % 3);
        LD_COL(oh, ow + 1, (pp + 2) % 3);
      } else {
        LD_COL(oh, ow + 1, (pp + 2) % 3);
      }
      float a0 = 0.f, a1 = 0.f, a2 = 0.f, a3 = 0.f;
#pragma unroll
      for (int dr = 0; dr < 3; dr++)
#pragma unroll
        for (int dc = 0; dc < 3; dc++) {
          const int sl = (pp + dc) % 3;
          const int wi = dr * 3 + dc;
          a0 = fmaf(w9[0][wi], act[dr][sl][0], a0);
          a1 = fmaf(w9[1][wi], act[dr][sl][1], a1);
          a2 = fmaf(w9[2][wi], act[dr][sl][2], a2);
          a3 = fmaf(w9[3][wi], act[dr][sl][3], a3);
        }
      union { u16 h[4]; uint2 v; } pk;
      pk.h[0] = f2bf(a0); pk.h[1] = f2bf(a1);
      pk.h[2] = f2bf(a2); pk.h[3] = f2bf(a3);
      *(uint2*)(&ash[p * AP + c4]) = pk.v;
    }
  }
  __syncthreads();
  int quad = lane >> 4;
  int lr = lane & 15;
  int nbase = wave * 128;
  f32x4 acc[4][8];
#pragma unroll
  for (int mt = 0; mt < 4; mt++)
#pragma unroll
    for (int nt = 0; nt < 8; nt++) acc[mt][nt] = (f32x4){0.f, 0.f, 0.f, 0.f};
  for (int kk = 0; kk < 256; kk += 32) {
    bf16x8 af[4];
#pragma unroll
    for (int mt = 0; mt < 4; mt++)
      af[mt] = *(const bf16x8*)(&ash[(mt * 16 + lr) * AP + kk + quad * 8]);
    bf16x8 bfr[8];
#pragma unroll
    for (int nt = 0; nt < 8; nt++)
      bfr[nt] = *(const bf16x8*)(bwb + (size_t)(nbase + nt * 16 + lr) * 256 + kk + quad * 8);
#pragma unroll
    for (int mt = 0; mt < 4; mt++)
#pragma unroll
      for (int nt = 0; nt < 8; nt++)
        acc[mt][nt] = __builtin_amdgcn_mfma_f32_16x16x32_bf16(af[mt], bfr[nt], acc[mt][nt], 0, 0, 0);
  }
  if (pass == 0) {
#pragma unroll
    for (int nt = 0; nt < 8; nt++) {
      float s = 0.f, q = 0.f;
#pragma unroll
      for (int mt = 0; mt < 4; mt++)
#pragma unroll
        for (int r = 0; r < 4; r++) {
          float v = acc[mt][nt][r];
          s += v; q = fmaf(v, v, q);
        }
      s += __shfl_xor(s, 16); s += __shfl_xor(s, 32);
      q += __shfl_xor(q, 16); q += __shfl_xor(q, 32);
      if (lane < 16) {
        int n = nbase + nt * 16 + lane;
        partials[(size_t)blockIdx.x * 1024 + n] = s;
        partials[(size_t)blockIdx.x * 1024 + 512 + n] = q;
      }
    }
  } else {
#pragma unroll
    for (int nt = 0; nt < 8; nt++) {
      int n = nbase + nt * 16 + lr;
      float scn = bn2p[n], shn = bn2p[512 + n];
      float s = 0.f;
#pragma unroll
      for (int mt = 0; mt < 4; mt++)
#pragma unroll
        for (int r = 0; r < 4; r++)
          s += fmaxf(fmaf(acc[mt][nt][r], scn, shn), 0.f);
      s += __shfl_xor(s, 16); s += __shfl_xor(s, 32);
      if (lane < 16)
        partials[(size_t)blockIdx.x * 512 + n] = s;
    }
  }
}

// ---------------- reductions ----------------
__global__ __launch_bounds__(256) void k_red1(const float* __restrict__ P, float* __restrict__ P2) {
  int blk = blockIdx.x;
  int t = threadIdx.x;
  float4 s = {0.f, 0.f, 0.f, 0.f};
  for (int r = 0; r < 49; r++) {
    float4 v = *(const float4*)(P + ((size_t)(blk * 49 + r)) * 1024 + t * 4);
    s.x += v.x; s.y += v.y; s.z += v.z; s.w += v.w;
  }
  *(float4*)(P2 + (size_t)blk * 1024 + t * 4) = s;
}

__global__ void k_red_bn2(const float* __restrict__ P2, const float* __restrict__ g,
                          const float* __restrict__ bb, float* __restrict__ par) {
  int c = blockIdx.x * 256 + threadIdx.x;
  float s = 0.f, q = 0.f;
  for (int i = 0; i < 64; i++) {
    s += P2[(size_t)i * 1024 + c];
    q += P2[(size_t)i * 1024 + 512 + c];
  }
  float m = s * (1.f / (float)NSTAT);
  float v = q * (1.f / (float)NSTAT) - m * m;
  float sc = g[c] * rsqrtf(v + EPS);
  par[c] = sc;
  par[512 + c] = bb[c] - m * sc;
}

__global__ void k_red_y(const float* __restrict__ P, float* __restrict__ yb) {
  int idx = blockIdx.x * 256 + threadIdx.x;
  int b = idx >> 9, c = idx & 511;
  float s = 0.f;
  for (int i = 0; i < 196; i++) s += P[(size_t)(b * 196 + i) * 512 + c];
  yb[idx] = s;
}

// ---------------- per-batch SE + enc_fc + ctx ----------------
__global__ __launch_bounds__(256) void k_se(const float* __restrict__ y,
    const float* __restrict__ se1, const float* __restrict__ se2,
    const float* __restrict__ encw, const float* __restrict__ encb,
    const float* __restrict__ vw, float* __restrict__ ctxb) {
  int b = blockIdx.x;
  int t = threadIdx.x;
  __shared__ __align__(16) float ybar[512];
  __shared__ __align__(16) float uu[128];
  __shared__ __align__(16) float ff[512];
  __shared__ __align__(16) float feats[512];
  for (int i = t; i < 512; i += 256) ybar[i] = y[b * 512 + i] * (1.f / 12544.f);
  __syncthreads();
  if (t < 128) {
    const float4* wr = (const float4*)(se1 + t * 512);
    const float4* xv = (const float4*)ybar;
    float a = 0.f;
    for (int k = 0; k < 128; k++) {
      float4 w4 = wr[k], x4 = xv[k];
      a = fmaf(w4.x, x4.x, a); a = fmaf(w4.y, x4.y, a);
      a = fmaf(w4.z, x4.z, a); a = fmaf(w4.w, x4.w, a);
    }
    uu[t] = fmaxf(a, 0.f);
  }
  __syncthreads();
  for (int c = t; c < 512; c += 256) {
    const float4* wr = (const float4*)(se2 + c * 128);
    const float4* xv = (const float4*)uu;
    float a = 0.f;
    for (int k = 0; k < 32; k++) {
      float4 w4 = wr[k], x4 = xv[k];
      a = fmaf(w4.x, x4.x, a); a = fmaf(w4.y, x4.y, a);
      a = fmaf(w4.z, x4.z, a); a = fmaf(w4.w, x4.w, a);
    }
    ff[c] = ybar[c] * sigm(a);
  }
  __syncthreads();
  for (int c = t; c < 512; c += 256) {
    const float4* wr = (const float4*)(encw + (size_t)c * 512);
    const float4* xv = (const float4*)ff;
    float a = encb[c];
    for (int k = 0; k < 128; k++) {
      float4 w4 = wr[k], x4 = xv[k];
      a = fmaf(w4.x, x4.x, a); a = fmaf(w4.y, x4.y, a);
      a = fmaf(w4.z, x4.z, a); a = fmaf(w4.w, x4.w, a);
    }
    feats[c] = a;
  }
  __syncthreads();
  for (int c = t; c < 512; c += 256) {
    const float4* wr = (const float4*)(vw + (size_t)c * 512);
    const float4* xv = (const float4*)feats;
    float a = 0.f;
    for (int k = 0; k < 128; k++) {
      float4 w4 = wr[k], x4 = xv[k];
      a = fmaf(w4.x, x4.x, a); a = fmaf(w4.y, x4.y, a);
      a = fmaf(w4.z, x4.z, a); a = fmaf(w4.w, x4.w, a);
    }
    ctxb[b * 512 + c] = a;
  }
}

// ---------------- gi split: ctx half once (K=512), emb half per step ----------------
// Round-19: k_gi3 unchanged at 121us after two ILP fixes -> NOT load-latency
// bound. Invariant across variants: 6-deep __shfl_xor tree = ~4.7M ds_bpermute
// on the shared LDS pipe ~ 60-120us. Fix: transpose wih emb-half ONCE
// (k_trans -> wihT[512][1536], k-major) so lane owns j (coalesced wihT reads),
// K is a serial per-lane loop, and emb[k][b] are wave-uniform LDS broadcasts.
// Zero shuffles. Per 2-k: 2 global + 8 broadcast ds_read_b128 + 32 FMA.
__global__ __launch_bounds__(256) void k_gctx(const float* __restrict__ ctxb,
    const float* __restrict__ wih, const float* __restrict__ bih, float* __restrict__ gictx) {
  int lb = threadIdx.x >> 4;
  int lj = threadIdx.x & 15;
  int j = blockIdx.x * 16 + lj;
  const float4* wr = (const float4*)(wih + (size_t)j * 1024 + 512);
  const float4* xv = (const float4*)(ctxb + lb * 512);
  float a = bih[j];
#pragma unroll 4
  for (int k = 0; k < 128; k++) {
    float4 w4 = wr[k], x4 = xv[k];
    a = fmaf(w4.x, x4.x, a); a = fmaf(w4.y, x4.y, a);
    a = fmaf(w4.z, x4.z, a); a = fmaf(w4.w, x4.w, a);
  }
  gictx[lb * 1536 + j] = a;
}

// one-time transpose of wih's emb half: wihT[k][j] = wih[j][k], k<512, j<1536
__global__ __launch_bounds__(256) void k_trans(const float* __restrict__ wih,
    float* __restrict__ wihT) {
  __shared__ float tile[32][33];
  int tx = threadIdx.x & 31, ty = threadIdx.x >> 5;   // 32 x 8
  int j0 = blockIdx.x * 32, k0 = blockIdx.y * 32;
#pragma unroll
  for (int i = 0; i < 4; i++)
    tile[ty + i * 8][tx] = wih[(size_t)(j0 + ty + i * 8) * 1024 + k0 + tx];
  __syncthreads();
#pragma unroll
  for (int i = 0; i < 4; i++)
    wihT[(size_t)(k0 + ty + i * 8) * 1536 + j0 + tx] = tile[tx][ty + i * 8];
}

__global__ __launch_bounds__(256) void k_gi4(const int* __restrict__ caps,
    const float* __restrict__ embed, const float* __restrict__ wihT,
    const float* __restrict__ gictx, float* __restrict__ gi) {
  __shared__ __align__(16) float semb[512][16];   // [k][b]
  int tid = threadIdx.x;
  int t = blockIdx.y;
  for (int i = tid; i < 8192; i += 256) {
    int k = i >> 4, b = i & 15;
    int tok = caps[b * 33 + t];
    semb[k][b] = embed[(size_t)tok * 512 + k];
  }
  __syncthreads();
  int wave = tid >> 6, lane = tid & 63;
  int j = (blockIdx.x * 4 + wave) * 64 + lane;   // 6 blocks.x * 4 waves * 64 = 1536 j
  float acc[16];
#pragma unroll
  for (int b = 0; b < 16; b++) acc[b] = 0.f;
  for (int k = 0; k < 512; k += 2) {
    float wv0 = wihT[(size_t)k * 1536 + j];
    float wv1 = wihT[(size_t)(k + 1) * 1536 + j];
    const f32x4* e0 = (const f32x4*)&semb[k][0];
    const f32x4* e1 = (const f32x4*)&semb[k + 1][0];
#pragma unroll
    for (int q = 0; q < 4; q++) {
      f32x4 a0 = e0[q], a1 = e1[q];
      acc[q * 4 + 0] = fmaf(wv0, a0[0], acc[q * 4 + 0]);
      acc[q * 4 + 1] = fmaf(wv0, a0[1], acc[q * 4 + 1]);
      acc[q * 4 + 2] = fmaf(wv0, a0[2], acc[q * 4 + 2]);
      acc[q * 4 + 3] = fmaf(wv0, a0[3], acc[q * 4 + 3]);
      acc[q * 4 + 0] = fmaf(wv1, a1[0], acc[q * 4 + 0]);
      acc[q * 4 + 1] = fmaf(wv1, a1[1], acc[q * 4 + 1]);
      acc[q * 4 + 2] = fmaf(wv1, a1[2], acc[q * 4 + 2]);
      acc[q * 4 + 3] = fmaf(wv1, a1[3], acc[q * 4 + 3]);
    }
  }
#pragma unroll
  for (int b = 0; b < 16; b++)
    gi[((size_t)t * 16 + b) * 1536 + j] = acc[b] + gictx[b * 1536 + j];
}

// ---------------- GRU single step (launched 32x; kernel boundary = barrier) ----------------
__global__ __launch_bounds__(192) void k_gru_step(const float* __restrict__ whh,
    const float* __restrict__ bhh, const float* __restrict__ gi_t,
    const float* __restrict__ h_in, float* __restrict__ h_out) {
  int g = blockIdx.x;
  int tid = threadIdx.x;
  int s = tid / 24;          // 0..7
  int r = tid - s * 24;      // 0..23
  int gate = r >> 3, lj = r & 7;
  int jj = g * 8 + lj;
  int R = gate * 512 + jj;
  float4 w[16];
  {
    const float4* wp = (const float4*)(whh + (size_t)R * 512 + s * 64);
#pragma unroll
    for (int i = 0; i < 16; i++) w[i] = wp[i];
  }
  __shared__ __align__(16) float hs[16][512];
  __shared__ float pr[8][24][16];   // [seg][row][batch]

  // stage h_t (plain vector loads; coherent via kernel boundary)
  {
    const float4* hp = (const float4*)h_in;
    float4* hd = (float4*)&hs[0][0];
    for (int i = tid; i < 2048; i += 192) hd[i] = hp[i];
  }
  __syncthreads();
  // per-thread partial dots: 16 batches x 64-wide segment
#pragma unroll
  for (int b = 0; b < 16; b++) {
    const float4* hv = (const float4*)&hs[b][s * 64];
    float a = 0.f;
#pragma unroll
    for (int k = 0; k < 16; k++) {
      float4 w4 = w[k], h4 = hv[k];
      a = fmaf(w4.x, h4.x, a); a = fmaf(w4.y, h4.y, a);
      a = fmaf(w4.z, h4.z, a); a = fmaf(w4.w, h4.w, a);
    }
    pr[s][r][b] = a;
  }
  __syncthreads();
  // combine gates + h update: threads 0..127, b=tid>>3, jl=tid&7
  if (tid < 128) {
    int b = tid >> 3, jl = tid & 7;
    int j = g * 8 + jl;
    float gh[3];
#pragma unroll
    for (int gg = 0; gg < 3; gg++) {
      int rr = gg * 8 + jl;
      float sum = bhh[gg * 512 + j];
#pragma unroll
      for (int ss = 0; ss < 8; ss++) sum += pr[ss][rr][b];
      gh[gg] = sum;
    }
    const float* gib = gi_t + (size_t)b * 1536;
    float rg = sigm(gib[j] + gh[0]);
    float z  = sigm(gib[j + 512] + gh[1]);
    float n  = tanhf(gib[j + 1024] + rg * gh[2]);
    float hp = hs[b][j];
    h_out[b * 512 + j] = (1.f - z) * n + z * hp;
  }
}

// ---------------- logits GEMM (bf16 MFMA) ----------------
__global__ __launch_bounds__(256) void k_fc(const float* __restrict__ A,
    const u16* __restrict__ Bwb, const float* __restrict__ bias, float* __restrict__ out) {
  __shared__ u16 ash[128 * 136];
  int tid = threadIdx.x;
  int wave = tid >> 6;
  int lane = tid & 63;
  int quad = lane >> 4;
  int lr = lane & 15;
  int N0 = blockIdx.x * 256;
  int M0 = blockIdx.y * 128;
  f32x4 acc[8][4];
#pragma unroll
  for (int mf = 0; mf < 8; mf++)
#pragma unroll
    for (int nf = 0; nf < 4; nf++) acc[mf][nf] = (f32x4){0.f, 0.f, 0.f, 0.f};
  int arow = tid >> 1;
  int acol = (tid & 1) * 64;
  for (int kc = 0; kc < 512; kc += 128) {
#pragma unroll
    for (int j = 0; j < 16; j++) {
      float4 v = *(const float4*)(A + (size_t)(M0 + arow) * 512 + kc + acol + j * 4);
      union { u16 h[4]; uint2 u; } pk;
      pk.h[0] = f2bf(v.x); pk.h[1] = f2bf(v.y); pk.h[2] = f2bf(v.z); pk.h[3] = f2bf(v.w);
      *(uint2*)(&ash[arow * 136 + acol + j * 4]) = pk.u;
    }
    __syncthreads();
#pragma unroll
    for (int ks = 0; ks < 128; ks += 32) {
      bf16x8 af[8];
#pragma unroll
      for (int mf = 0; mf < 8; mf++)
        af[mf] = *(const bf16x8*)(&ash[(mf * 16 + lr) * 136 + ks + quad * 8]);
      bf16x8 bf[4];
#pragma unroll
      for (int nf = 0; nf < 4; nf++) {
        int n = N0 + wave * 64 + nf * 16 + lr;
        bf[nf] = *(const bf16x8*)(Bwb + (size_t)n * 512 + kc + ks + quad * 8);
      }
#pragma unroll
      for (int mf = 0; mf < 8; mf++)
#pragma unroll
        for (int nf = 0; nf < 4; nf++)
          acc[mf][nf] = __builtin_amdgcn_mfma_f32_16x16x32_bf16(af[mf], bf[nf], acc[mf][nf], 0, 0, 0);
    }
    __syncthreads();
  }
#pragma unroll
  for (int nf = 0; nf < 4; nf++) {
    int j = N0 + wave * 64 + nf * 16 + lr;
    float bv = bias[j];
#pragma unroll
    for (int mf = 0; mf < 8; mf++)
#pragma unroll
      for (int r = 0; r < 4; r++) {
        int m = M0 + mf * 16 + quad * 4 + r;   // m = t*16 + b
        int orow = (m & 15) * 32 + (m >> 4);   // out row = b*32 + t
        out[(size_t)orow * 32000 + j] = acc[mf][nf][r] + bv;
      }
  }
}

extern "C" void kernel_launch(void* const* d_in, const int* in_sizes, int n_in,
                              void* d_out, int out_size, void* d_ws, size_t ws_size,
                              hipStream_t stream) {
  const float* images  = (const float*)d_in[0];
  const int*   caps    = (const int*)d_in[1];
  const float* conv1_w = (const float*)d_in[2];
  const float* bn1_g   = (const float*)d_in[3];
  const float* bn1_b   = (const float*)d_in[4];
  const float* dw_w    = (const float*)d_in[5];
  const float* pw_w    = (const float*)d_in[6];
  const float* bn2_g   = (const float*)d_in[7];
  const float* bn2_b   = (const float*)d_in[8];
  const float* se1     = (const float*)d_in[9];
  const float* se2     = (const float*)d_in[10];
  const float* encw    = (const float*)d_in[11];
  const float* encb    = (const float*)d_in[12];
  const float* embed   = (const float*)d_in[13];
  const float* vw      = (const float*)d_in[16];
  const float* wih     = (const float*)d_in[17];
  const float* whh     = (const float*)d_in[18];
  const float* bih     = (const float*)d_in[19];
  const float* bhh     = (const float*)d_in[20];
  const float* fcw     = (const float*)d_in[21];
  const float* fcb     = (const float*)d_in[22];
  float* out = (float*)d_out;

  const bool big = ws_size >= (size_t)230 * 1000 * 1000;

  char* ws = (char*)d_ws;
  size_t off = 0;
  auto alloc = [&](size_t bytes) {
    void* p = ws + off;
    off = (off + bytes + 255) & ~(size_t)255;
    return p;
  };
  u16* conv1out = (u16*)alloc((size_t)51380224 * 2);
  u16* fcwb     = (u16*)conv1out;                       // alias (dead after dw/pwpass)
  u16* dwout    = big ? (u16*)alloc((size_t)51380224 * 2) : (u16*)nullptr;
  u16* bwb      = (u16*)alloc((size_t)131072 * 2);
  float* partials = (float*)alloc((size_t)3136 * 1024 * 4);
  float* p2     = (float*)alloc((size_t)64 * 1024 * 4);
  float* stats1 = (float*)alloc(512 * 4);
  float* h_all  = (float*)alloc((size_t)33 * 8192 * 4);
  float* bn1p   = (float*)alloc(512 * 4);
  float* bn2p   = (float*)alloc(1024 * 4);
  float* yb     = (float*)alloc(8192 * 4);
  float* ctxb   = (float*)alloc(8192 * 4);
  float* gictx  = (float*)alloc((size_t)16 * 1536 * 4);
  float* wihT   = (float*)alloc((size_t)512 * 1536 * 4);
  float* gi     = (float*)alloc((size_t)32 * 16 * 1536 * 4);
  (void)in_sizes; (void)n_in; (void)out_size;

  hipMemsetAsync(stats1, 0, 512 * 4, stream);
  hipMemsetAsync(h_all, 0, 8192 * 4, stream);   // h0 = 0

  k_conv1<<<896, 256, 0, stream>>>(images, conv1_w, conv1out, stats1);
  k_bnfin<<<1, 256, 0, stream>>>(stats1, bn1_g, bn1_b, bn1p, 256, 1.f / (float)NSTAT);
  k_cvt4<<<128, 256, 0, stream>>>(pw_w, bwb, 32768);
  {
    dim3 gtr(48, 16);
    k_trans<<<gtr, 256, 0, stream>>>(wih, wihT);
  }

  if (big) {
    k_dws<<<3136, 256, 0, stream>>>(conv1out, bn1p, dw_w, dwout);
    k_cvt4<<<16000, 256, 0, stream>>>(fcw, fcwb, 4096000);
    dim3 gpw(3136, 2);
    k_pws<<<gpw, 256, 0, stream>>>(dwout, bwb, partials, bn2p, 0);
    k_red1<<<64, 256, 0, stream>>>(partials, p2);
    k_red_bn2<<<2, 256, 0, stream>>>(p2, bn2_g, bn2_b, bn2p);
    k_pws<<<gpw, 256, 0, stream>>>(dwout, bwb, partials, bn2p, 1);
  } else {
    k_pwpass<<<3136, 256, 0, stream>>>(conv1out, bn1p, dw_w, bwb, partials, bn2p, 0);
    k_red1<<<64, 256, 0, stream>>>(partials, p2);
    k_red_bn2<<<2, 256, 0, stream>>>(p2, bn2_g, bn2_b, bn2p);
    k_pwpass<<<3136, 256, 0, stream>>>(conv1out, bn1p, dw_w, bwb, partials, bn2p, 1);
    k_cvt4<<<16000, 256, 0, stream>>>(fcw, fcwb, 4096000);
  }
  k_red_y<<<32, 256, 0, stream>>>(partials, yb);
  k_se<<<16, 256, 0, stream>>>(yb, se1, se2, encw, encb, vw, ctxb);
  k_gctx<<<96, 256, 0, stream>>>(ctxb, wih, bih, gictx);
  dim3 ggi4(6, 32);
  k_gi4<<<ggi4, 256, 0, stream>>>(caps, embed, wihT, gictx, gi);
  for (int t = 0; t < 32; t++)
    k_gru_step<<<64, 192, 0, stream>>>(whh, bhh, gi + (size_t)t * 16 * 1536,
                                       h_all + (size_t)t * 8192, h_all + (size_t)(t + 1) * 8192);
  dim3 gfc(125, 4);
  k_fc<<<gfc, 256, 0, stream>>>(h_all + 8192, fcwb, fcb, out);
}